// Round 1
// baseline (978.944 us; speedup 1.0000x reference)
//
#include <hip/hip_runtime.h>
#include <hip/hip_bf16.h>

#define G 5
#define B 8
#define CIN 320
#define CIN_G 64
#define COUT 480
#define COUT_G 96
#define J 256
#define K 62
#define NPOS (J*K)              // 15872
#define NPOS_TILES (NPOS/256)   // 62
#define NSTAT (B*NPOS)          // 126976
#define BN_EPS 1e-5f

__device__ __forceinline__ float ldconv(const float* p, size_t i) { return p[i]; }
__device__ __forceinline__ float ldconv(const __hip_bfloat16* p, size_t i) { return __bfloat162float(p[i]); }

// ---------------- conv1: grouped 1x1, x[b,g*64+c,pos] * W1[g,o,c] -> h (bf16)
__global__ __launch_bounds__(256) void k_conv1(
    const float* __restrict__ x, const float* __restrict__ W1,
    __hip_bfloat16* __restrict__ h)
{
    __shared__ float w[COUT_G * CIN_G];           // 24 KB
    const int b = blockIdx.z, g = blockIdx.y;
    const int pos = blockIdx.x * 256 + threadIdx.x;
    for (int i = threadIdx.x; i < COUT_G * CIN_G; i += 256)
        w[i] = W1[g * COUT_G * CIN_G + i];
    __syncthreads();

    float xs[CIN_G];
    const float* xp = x + ((size_t)(b * CIN + g * CIN_G)) * NPOS + pos;
#pragma unroll
    for (int c = 0; c < CIN_G; ++c) xs[c] = xp[(size_t)c * NPOS];

    __hip_bfloat16* hp = h + ((size_t)(b * COUT + g * COUT_G)) * NPOS + pos;
    for (int o = 0; o < COUT_G; ++o) {
        float acc = 0.f;
#pragma unroll
        for (int c = 0; c < CIN_G; ++c) acc += xs[c] * w[o * CIN_G + c];
        hp[(size_t)o * NPOS] = __float2bfloat16(acc);
    }
}

// ---------------- per-channel sum / sumsq over (B, pos)
template <typename T>
__global__ __launch_bounds__(256) void k_stats(
    const T* __restrict__ v, float* __restrict__ sum, float* __restrict__ sq)
{
    const int ch = blockIdx.y;
    const int pos = blockIdx.x * 256 + threadIdx.x;
    float s = 0.f, q = 0.f;
#pragma unroll
    for (int b = 0; b < B; ++b) {
        float t = ldconv(v, ((size_t)(b * COUT + ch)) * NPOS + pos);
        s += t; q += t * t;
    }
#pragma unroll
    for (int off = 32; off >= 1; off >>= 1) {
        s += __shfl_down(s, off);
        q += __shfl_down(q, off);
    }
    __shared__ float ls[4], lq[4];
    const int wid = threadIdx.x >> 6, lane = threadIdx.x & 63;
    if (lane == 0) { ls[wid] = s; lq[wid] = q; }
    __syncthreads();
    if (threadIdx.x == 0) {
        atomicAdd(&sum[ch], ls[0] + ls[1] + ls[2] + ls[3]);
        atomicAdd(&sq[ch],  lq[0] + lq[1] + lq[2] + lq[3]);
    }
}

// ---------------- stats -> affine coefs: a = gamma*rstd, b = beta - mean*a
__global__ void k_finalize(const float* __restrict__ sum, const float* __restrict__ sq,
                           const float* __restrict__ gamma, const float* __restrict__ beta,
                           float* __restrict__ a, float* __restrict__ bb)
{
    int ch = blockIdx.x * blockDim.x + threadIdx.x;
    if (ch < COUT) {
        const float invN = 1.f / (float)NSTAT;
        float mean = sum[ch] * invN;
        float var  = sq[ch] * invN - mean * mean;
        float rstd = rsqrtf(var + BN_EPS);
        float av = gamma[ch] * rstd;
        a[ch]  = av;
        bb[ch] = beta[ch] - mean * av;
    }
}

// ---------------- conv2: BN1-affine + ELU fused on load, then 96x96 mix -> h2 (fp32, d_out)
__global__ __launch_bounds__(256) void k_conv2(
    const __hip_bfloat16* __restrict__ h, const float* __restrict__ W2,
    const float* __restrict__ a1, const float* __restrict__ b1,
    float* __restrict__ h2)
{
    __shared__ float w[COUT_G * COUT_G];          // 36 KB
    const int b = blockIdx.z, g = blockIdx.y;
    const int pos = blockIdx.x * 256 + threadIdx.x;
    for (int i = threadIdx.x; i < COUT_G * COUT_G; i += 256)
        w[i] = W2[g * COUT_G * COUT_G + i];
    __syncthreads();

    float es[COUT_G];
    const __hip_bfloat16* hp = h + ((size_t)(b * COUT + g * COUT_G)) * NPOS + pos;
#pragma unroll
    for (int c = 0; c < COUT_G; ++c) {
        float v = __bfloat162float(hp[(size_t)c * NPOS]);
        const int ch = g * COUT_G + c;
        float e = a1[ch] * v + b1[ch];
        es[c] = e > 0.f ? e : expm1f(e);
    }

    float* op = h2 + ((size_t)(b * COUT + g * COUT_G)) * NPOS + pos;
    for (int o = 0; o < COUT_G; ++o) {
        float acc = 0.f;
#pragma unroll
        for (int c = 0; c < COUT_G; ++c) acc += es[c] * w[o * COUT_G + c];
        op[(size_t)o * NPOS] = acc;
    }
}

// ---------------- adjacency: y[b,ch,j,p] = sum_k (a2*h2 + b2)[b,ch,j,k] * L[g,k,p], in-place on d_out
__global__ __launch_bounds__(256) void k_adj(
    float* __restrict__ y, const float* __restrict__ L,
    const float* __restrict__ a2, const float* __restrict__ b2)
{
    __shared__ float slab[NPOS];      // 63.5 KB: whole (b,ch) J*K slab
    __shared__ float Ll[K * K];       // 15.4 KB
    const int ch = blockIdx.x, b = blockIdx.y;
    const int g = ch / COUT_G;
    const float av = a2[ch], bv = b2[ch];
    float* base = y + ((size_t)(b * COUT + ch)) * NPOS;

    for (int i = threadIdx.x; i < NPOS; i += 256)
        slab[i] = av * base[i] + bv;                // BN2 affine fused
    for (int i = threadIdx.x; i < K * K; i += 256)
        Ll[i] = L[g * K * K + i];
    __syncthreads();

    const int j = threadIdx.x;                      // J == 256 == blockDim
    float outs[K];
#pragma unroll
    for (int p = 0; p < K; ++p) outs[p] = 0.f;
    for (int k = 0; k < K; ++k) {
        float rv = slab[j * K + k];
#pragma unroll
        for (int p = 0; p < K; ++p) outs[p] += rv * Ll[k * K + p];
    }
    // write own row back to LDS (each thread touches only its own row), then coalesced store
#pragma unroll
    for (int p = 0; p < K; ++p) slab[j * K + p] = outs[p];
    __syncthreads();
    for (int i = threadIdx.x; i < NPOS; i += 256)
        base[i] = slab[i];
}

extern "C" void kernel_launch(void* const* d_in, const int* in_sizes, int n_in,
                              void* d_out, int out_size, void* d_ws, size_t ws_size,
                              hipStream_t stream)
{
    const float* x      = (const float*)d_in[0];
    const float* L      = (const float*)d_in[1];
    const float* W1     = (const float*)d_in[2];
    const float* W2     = (const float*)d_in[3];
    const float* gamma1 = (const float*)d_in[4];
    const float* beta1  = (const float*)d_in[5];
    const float* gamma2 = (const float*)d_in[6];
    const float* beta2  = (const float*)d_in[7];
    float* h2 = (float*)d_out;

    __hip_bfloat16* h = (__hip_bfloat16*)d_ws;
    const size_t hbytes = (size_t)B * COUT * NPOS * sizeof(__hip_bfloat16);  // ~122 MB
    float* stats = (float*)((char*)d_ws + hbytes);
    float* sum1 = stats;        float* sq1 = stats + 480;
    float* sum2 = stats + 960;  float* sq2 = stats + 1440;
    float* a1   = stats + 1920; float* b1  = stats + 2400;
    float* a2   = stats + 2880; float* b2  = stats + 3360;

    hipMemsetAsync(stats, 0, 4 * 480 * sizeof(float), stream);

    dim3 gridc(NPOS_TILES, G, B);       // 62 x 5 x 8
    dim3 grids(NPOS_TILES, COUT);       // 62 x 480
    dim3 grida(COUT, B);                // 480 x 8

    k_conv1<<<gridc, 256, 0, stream>>>(x, W1, h);
    k_stats<__hip_bfloat16><<<grids, 256, 0, stream>>>(h, sum1, sq1);
    k_finalize<<<2, 256, 0, stream>>>(sum1, sq1, gamma1, beta1, a1, b1);
    k_conv2<<<gridc, 256, 0, stream>>>(h, W2, a1, b1, h2);
    k_stats<float><<<grids, 256, 0, stream>>>(h2, sum2, sq2);
    k_finalize<<<2, 256, 0, stream>>>(sum2, sq2, gamma2, beta2, a2, b2);
    k_adj<<<grida, 256, 0, stream>>>(h2, L, a2, b2);
}

// Round 2
// 427.586 us; speedup vs baseline: 2.2895x; 2.2895x over previous
//
#include <hip/hip_runtime.h>
#include <hip/hip_bf16.h>

#define G 5
#define B 8
#define CIN 320
#define CIN_G 64
#define COUT 480
#define COUT_G 96
#define NPOS 15872
#define NPOS_TILES 62          // NPOS / 256
#define NSTAT (B*NPOS)
#define BN_EPS 1e-5f
#define C8H 12                 // COUT_G/8 : k-pack groups of h / h2-producer

typedef float  f32x4  __attribute__((ext_vector_type(4)));
typedef __bf16 bf16x8 __attribute__((ext_vector_type(8)));
typedef __bf16 bf16x4 __attribute__((ext_vector_type(4)));

// ---------------- conv1 (MFMA): h[b][g][c8][pos][8] (bf16 k-packed) = W1 x
__global__ __launch_bounds__(256) void k_conv1(
    const float* __restrict__ x, const float* __restrict__ W1,
    __bf16* __restrict__ h)
{
    __shared__ __bf16 wl[COUT_G * CIN_G];        // 12 KB
    const int b = blockIdx.z, g = blockIdx.y;
    for (int i = threadIdx.x; i < COUT_G * CIN_G; i += 256)
        wl[i] = (__bf16)W1[g * COUT_G * CIN_G + i];
    __syncthreads();

    const int wid = threadIdx.x >> 6, lane = threadIdx.x & 63;
    const int lg = lane >> 4, lr = lane & 15;
    const int pos0 = blockIdx.x * 256 + wid * 64;

    const float* xb = x + ((size_t)b * CIN + g * CIN_G) * NPOS;

    f32x4 acc[6][4];
#pragma unroll
    for (int mt = 0; mt < 6; ++mt)
#pragma unroll
        for (int nt = 0; nt < 4; ++nt) acc[mt][nt] = (f32x4){0.f,0.f,0.f,0.f};

#pragma unroll
    for (int ks = 0; ks < 2; ++ks) {
        const int c0 = ks * 32 + lg * 8;
        bf16x8 af[6];
#pragma unroll
        for (int mt = 0; mt < 6; ++mt)
            af[mt] = *(const bf16x8*)&wl[(mt * 16 + lr) * CIN_G + c0];
#pragma unroll
        for (int nt = 0; nt < 4; ++nt) {
            const int pos = pos0 + nt * 16 + lr;
            bf16x8 bfv;
#pragma unroll
            for (int i = 0; i < 8; ++i)
                bfv[i] = (__bf16)xb[(size_t)(c0 + i) * NPOS + pos];
#pragma unroll
            for (int mt = 0; mt < 6; ++mt)
                acc[mt][nt] = __builtin_amdgcn_mfma_f32_16x16x32_bf16(af[mt], bfv, acc[mt][nt], 0, 0, 0);
        }
    }

    // store k-packed: elem offset = ((c8)*NPOS + pos)*8 + (o&7)
    __bf16* hb = h + (((size_t)b * G + g) * C8H) * NPOS * 8;
#pragma unroll
    for (int mt = 0; mt < 6; ++mt) {
        const int o0 = mt * 16 + lg * 4;          // 4 consecutive o
        const size_t rowoff = (size_t)(o0 >> 3) * NPOS * 8 + (o0 & 7);
#pragma unroll
        for (int nt = 0; nt < 4; ++nt) {
            const int pos = pos0 + nt * 16 + lr;
            bf16x4 pv;
#pragma unroll
            for (int r = 0; r < 4; ++r) pv[r] = (__bf16)acc[mt][nt][r];
            *(bf16x4*)&hb[rowoff + (size_t)pos * 8] = pv;
        }
    }
}

// ---------------- stats over k-packed bf16 tensor (COUT channels)
__global__ __launch_bounds__(256) void k_stats_kp(
    const __bf16* __restrict__ h, float* __restrict__ sum, float* __restrict__ sq)
{
    const int gc8 = blockIdx.y;                 // g*C8H + c8, 0..59
    const int g = gc8 / C8H, c8 = gc8 % C8H;
    const int pos = blockIdx.x * 256 + threadIdx.x;
    float s[8], q[8];
#pragma unroll
    for (int i = 0; i < 8; ++i) { s[i] = 0.f; q[i] = 0.f; }
#pragma unroll
    for (int b = 0; b < B; ++b) {
        const bf16x8 v = *(const bf16x8*)&h[((((size_t)b * G + g) * C8H + c8) * NPOS + pos) * 8];
#pragma unroll
        for (int i = 0; i < 8; ++i) { float t = (float)v[i]; s[i] += t; q[i] += t * t; }
    }
#pragma unroll
    for (int i = 0; i < 8; ++i)
#pragma unroll
        for (int off = 32; off >= 1; off >>= 1) {
            s[i] += __shfl_down(s[i], off);
            q[i] += __shfl_down(q[i], off);
        }
    __shared__ float red[4][16];
    const int wid = threadIdx.x >> 6, lane = threadIdx.x & 63;
    if (lane == 0) {
#pragma unroll
        for (int i = 0; i < 8; ++i) { red[wid][i] = s[i]; red[wid][8 + i] = q[i]; }
    }
    __syncthreads();
    if (threadIdx.x < 16) {
        float v = red[0][threadIdx.x] + red[1][threadIdx.x] + red[2][threadIdx.x] + red[3][threadIdx.x];
        const int ch = g * COUT_G + c8 * 8 + (threadIdx.x & 7);
        atomicAdd(threadIdx.x < 8 ? &sum[ch] : &sq[ch], v);
    }
}

// ---------------- stats over fp32 standard layout
__global__ __launch_bounds__(256) void k_stats_f32(
    const float* __restrict__ v, float* __restrict__ sum, float* __restrict__ sq)
{
    const int ch = blockIdx.y;
    const int pos = blockIdx.x * 256 + threadIdx.x;
    float s = 0.f, q = 0.f;
#pragma unroll
    for (int b = 0; b < B; ++b) {
        float t = v[((size_t)(b * COUT + ch)) * NPOS + pos];
        s += t; q += t * t;
    }
#pragma unroll
    for (int off = 32; off >= 1; off >>= 1) {
        s += __shfl_down(s, off);
        q += __shfl_down(q, off);
    }
    __shared__ float ls[4], lq[4];
    const int wid = threadIdx.x >> 6, lane = threadIdx.x & 63;
    if (lane == 0) { ls[wid] = s; lq[wid] = q; }
    __syncthreads();
    if (threadIdx.x == 0) {
        atomicAdd(&sum[ch], ls[0] + ls[1] + ls[2] + ls[3]);
        atomicAdd(&sq[ch],  lq[0] + lq[1] + lq[2] + lq[3]);
    }
}

// ---------------- stats -> affine coefs: a = gamma*rstd, b = beta - mean*a
__global__ void k_finalize(const float* __restrict__ sum, const float* __restrict__ sq,
                           const float* __restrict__ gamma, const float* __restrict__ beta,
                           float* __restrict__ a, float* __restrict__ bb)
{
    int ch = blockIdx.x * blockDim.x + threadIdx.x;
    if (ch < COUT) {
        const float invN = 1.f / (float)NSTAT;
        float mean = sum[ch] * invN;
        float var  = sq[ch] * invN - mean * mean;
        float rstd = rsqrtf(var + BN_EPS);
        float av = gamma[ch] * rstd;
        a[ch]  = av;
        bb[ch] = beta[ch] - mean * av;
    }
}

// ---------------- conv2 (MFMA): h2(fp32 std, d_out) = W2 * elu(affine(h))
__global__ __launch_bounds__(256) void k_conv2(
    const __bf16* __restrict__ h, const float* __restrict__ W2,
    const float* __restrict__ a1, const float* __restrict__ b1,
    float* __restrict__ h2)
{
    __shared__ __bf16 wl[COUT_G * COUT_G];       // 18 KB
    __shared__ float a1l[COUT_G], b1l[COUT_G];
    const int b = blockIdx.z, g = blockIdx.y;
    for (int i = threadIdx.x; i < COUT_G * COUT_G; i += 256)
        wl[i] = (__bf16)W2[g * COUT_G * COUT_G + i];
    if (threadIdx.x < COUT_G) {
        a1l[threadIdx.x] = a1[g * COUT_G + threadIdx.x];
        b1l[threadIdx.x] = b1[g * COUT_G + threadIdx.x];
    }
    __syncthreads();

    const int wid = threadIdx.x >> 6, lane = threadIdx.x & 63;
    const int lg = lane >> 4, lr = lane & 15;
    const int pos0 = blockIdx.x * 256 + wid * 64;

    const __bf16* hb = h + (((size_t)b * G + g) * C8H) * NPOS * 8;

    f32x4 acc[6][4];
#pragma unroll
    for (int mt = 0; mt < 6; ++mt)
#pragma unroll
        for (int nt = 0; nt < 4; ++nt) acc[mt][nt] = (f32x4){0.f,0.f,0.f,0.f};

#pragma unroll
    for (int ks = 0; ks < 3; ++ks) {
        const int c0 = ks * 32 + lg * 8;
        bf16x8 af[6];
#pragma unroll
        for (int mt = 0; mt < 6; ++mt)
            af[mt] = *(const bf16x8*)&wl[(mt * 16 + lr) * COUT_G + c0];
        float av[8], bv[8];
#pragma unroll
        for (int i = 0; i < 8; ++i) { av[i] = a1l[c0 + i]; bv[i] = b1l[c0 + i]; }
#pragma unroll
        for (int nt = 0; nt < 4; ++nt) {
            const int pos = pos0 + nt * 16 + lr;
            const bf16x8 hv = *(const bf16x8*)&hb[((size_t)(ks * 4 + lg) * NPOS + pos) * 8];
            bf16x8 ef;
#pragma unroll
            for (int i = 0; i < 8; ++i) {
                float t = av[i] * (float)hv[i] + bv[i];
                t = t > 0.f ? t : (__expf(t) - 1.f);
                ef[i] = (__bf16)t;
            }
#pragma unroll
            for (int mt = 0; mt < 6; ++mt)
                acc[mt][nt] = __builtin_amdgcn_mfma_f32_16x16x32_bf16(af[mt], ef, acc[mt][nt], 0, 0, 0);
        }
    }

    float* ob = h2 + ((size_t)b * COUT + g * COUT_G) * NPOS;
#pragma unroll
    for (int mt = 0; mt < 6; ++mt) {
        const int o0 = mt * 16 + lg * 4;
#pragma unroll
        for (int nt = 0; nt < 4; ++nt) {
            const int pos = pos0 + nt * 16 + lr;
#pragma unroll
            for (int r = 0; r < 4; ++r)
                ob[(size_t)(o0 + r) * NPOS + pos] = acc[mt][nt][r];
        }
    }
}

// ---------------- adjacency: y = (a2*h2+b2) @ L per (b,ch) slab, in-place on d_out
__global__ __launch_bounds__(256) void k_adj(
    float* __restrict__ y, const float* __restrict__ L,
    const float* __restrict__ a2, const float* __restrict__ b2)
{
    __shared__ float slab[NPOS];      // 63.5 KB
    __shared__ float Ll[62 * 62];     // 15.4 KB
    const int ch = blockIdx.x, b = blockIdx.y;
    const int g = ch / COUT_G;
    const float av = a2[ch], bv = b2[ch];
    float* base = y + ((size_t)(b * COUT + ch)) * NPOS;

    for (int i = threadIdx.x; i < NPOS; i += 256)
        slab[i] = av * base[i] + bv;
    for (int i = threadIdx.x; i < 62 * 62; i += 256)
        Ll[i] = L[g * 62 * 62 + i];
    __syncthreads();

    const int j = threadIdx.x;
    float outs[62];
#pragma unroll
    for (int p = 0; p < 62; ++p) outs[p] = 0.f;
    for (int k = 0; k < 62; ++k) {
        float rv = slab[j * 62 + k];
#pragma unroll
        for (int p = 0; p < 62; ++p) outs[p] += rv * Ll[k * 62 + p];
    }
#pragma unroll
    for (int p = 0; p < 62; ++p) slab[j * 62 + p] = outs[p];
    __syncthreads();
    for (int i = threadIdx.x; i < NPOS; i += 256)
        base[i] = slab[i];
}

extern "C" void kernel_launch(void* const* d_in, const int* in_sizes, int n_in,
                              void* d_out, int out_size, void* d_ws, size_t ws_size,
                              hipStream_t stream)
{
    const float* x      = (const float*)d_in[0];
    const float* L      = (const float*)d_in[1];
    const float* W1     = (const float*)d_in[2];
    const float* W2     = (const float*)d_in[3];
    const float* gamma1 = (const float*)d_in[4];
    const float* beta1  = (const float*)d_in[5];
    const float* gamma2 = (const float*)d_in[6];
    const float* beta2  = (const float*)d_in[7];
    float* h2 = (float*)d_out;

    __bf16* h = (__bf16*)d_ws;
    const size_t hbytes = (size_t)B * COUT * NPOS * sizeof(__bf16);   // ~122 MB
    float* stats = (float*)((char*)d_ws + hbytes);
    float* sum1 = stats;        float* sq1 = stats + 480;
    float* sum2 = stats + 960;  float* sq2 = stats + 1440;
    float* a1   = stats + 1920; float* b1  = stats + 2400;
    float* a2   = stats + 2880; float* b2  = stats + 3360;

    hipMemsetAsync(stats, 0, 4 * 480 * sizeof(float), stream);

    dim3 gridc(NPOS_TILES, G, B);        // 62 x 5 x 8
    dim3 gridskp(NPOS_TILES, G * C8H);   // 62 x 60
    dim3 grids(NPOS_TILES, COUT);        // 62 x 480
    dim3 grida(COUT, B);                 // 480 x 8

    k_conv1<<<gridc, 256, 0, stream>>>(x, W1, h);
    k_stats_kp<<<gridskp, 256, 0, stream>>>(h, sum1, sq1);
    k_finalize<<<2, 256, 0, stream>>>(sum1, sq1, gamma1, beta1, a1, b1);
    k_conv2<<<gridc, 256, 0, stream>>>(h, W2, a1, b1, h2);
    k_stats_f32<<<grids, 256, 0, stream>>>(h2, sum2, sq2);
    k_finalize<<<2, 256, 0, stream>>>(sum2, sq2, gamma2, beta2, a2, b2);
    k_adj<<<grida, 256, 0, stream>>>(h2, L, a2, b2);
}

// Round 3
// 332.420 us; speedup vs baseline: 2.9449x; 1.2863x over previous
//
#include <hip/hip_runtime.h>
#include <hip/hip_bf16.h>

#define G 5
#define B 8
#define CIN 320
#define CIN_G 64
#define COUT 480
#define COUT_G 96
#define NPOS 15872
#define NPOS_TILES 62
#define NSTAT (B*NPOS)
#define BN_EPS 1e-5f
#define C8H 12
#define KDIM 62

typedef float  f32x4  __attribute__((ext_vector_type(4)));
typedef __bf16 bf16x8 __attribute__((ext_vector_type(8)));
typedef __bf16 bf16x4 __attribute__((ext_vector_type(4)));

// ---------------- conv1 (MFMA): h[b][g][c8][pos][8] (bf16 k-packed) = W1 x ; fused BN1 stats
__global__ __launch_bounds__(256) void k_conv1(
    const float* __restrict__ x, const float* __restrict__ W1,
    __bf16* __restrict__ h, float* __restrict__ sum1, float* __restrict__ sq1)
{
    __shared__ __bf16 wl[COUT_G * 72];           // pad 64->72: row stride 144B, 2-way banks
    __shared__ float st[COUT_G * 2];
    const int b = blockIdx.z, g = blockIdx.y;
    for (int i = threadIdx.x; i < COUT_G * CIN_G; i += 256) {
        const int o = i >> 6, c = i & 63;
        wl[o * 72 + c] = (__bf16)W1[g * COUT_G * CIN_G + i];
    }
    if (threadIdx.x < COUT_G * 2) st[threadIdx.x] = 0.f;
    __syncthreads();

    const int wid = threadIdx.x >> 6, lane = threadIdx.x & 63;
    const int lg = lane >> 4, lr = lane & 15;
    const int pos0 = blockIdx.x * 256 + wid * 64;

    const float* xb = x + ((size_t)b * CIN + g * CIN_G) * NPOS;

    f32x4 acc[6][4];
#pragma unroll
    for (int mt = 0; mt < 6; ++mt)
#pragma unroll
        for (int nt = 0; nt < 4; ++nt) acc[mt][nt] = (f32x4){0.f,0.f,0.f,0.f};

#pragma unroll
    for (int ks = 0; ks < 2; ++ks) {
        const int c0 = ks * 32 + lg * 8;
        bf16x8 af[6];
#pragma unroll
        for (int mt = 0; mt < 6; ++mt)
            af[mt] = *(const bf16x8*)&wl[(mt * 16 + lr) * 72 + c0];
#pragma unroll
        for (int nt = 0; nt < 4; ++nt) {
            const int pos = pos0 + nt * 16 + lr;
            bf16x8 bfv;
#pragma unroll
            for (int i = 0; i < 8; ++i)
                bfv[i] = (__bf16)xb[(size_t)(c0 + i) * NPOS + pos];
#pragma unroll
            for (int mt = 0; mt < 6; ++mt)
                acc[mt][nt] = __builtin_amdgcn_mfma_f32_16x16x32_bf16(af[mt], bfv, acc[mt][nt], 0, 0, 0);
        }
    }

    // store k-packed for conv2
    __bf16* hb = h + (((size_t)b * G + g) * C8H) * NPOS * 8;
#pragma unroll
    for (int mt = 0; mt < 6; ++mt) {
        const int o0 = mt * 16 + lg * 4;
        const size_t rowoff = (size_t)(o0 >> 3) * NPOS * 8 + (o0 & 7);
#pragma unroll
        for (int nt = 0; nt < 4; ++nt) {
            const int pos = pos0 + nt * 16 + lr;
            bf16x4 pv;
#pragma unroll
            for (int r = 0; r < 4; ++r) pv[r] = (__bf16)acc[mt][nt][r];
            *(bf16x4*)&hb[rowoff + (size_t)pos * 8] = pv;
        }
    }

    // fused stats: channel o = mt*16+lg*4+r, summed over nt and lr
#pragma unroll
    for (int mt = 0; mt < 6; ++mt) {
#pragma unroll
        for (int r = 0; r < 4; ++r) {
            float s = 0.f, q = 0.f;
#pragma unroll
            for (int nt = 0; nt < 4; ++nt) {
                const float v = acc[mt][nt][r];
                s += v; q += v * v;
            }
#pragma unroll
            for (int m = 1; m <= 8; m <<= 1) {
                s += __shfl_xor(s, m);
                q += __shfl_xor(q, m);
            }
            if (lr == 0) {
                atomicAdd(&st[(mt * 16 + lg * 4 + r) * 2], s);
                atomicAdd(&st[(mt * 16 + lg * 4 + r) * 2 + 1], q);
            }
        }
    }
    __syncthreads();
    if (threadIdx.x < COUT_G) {
        atomicAdd(&sum1[g * COUT_G + threadIdx.x], st[threadIdx.x * 2]);
        atomicAdd(&sq1[g * COUT_G + threadIdx.x], st[threadIdx.x * 2 + 1]);
    }
}

// ---------------- stats -> affine coefs
__global__ void k_finalize(const float* __restrict__ sum, const float* __restrict__ sq,
                           const float* __restrict__ gamma, const float* __restrict__ beta,
                           float* __restrict__ a, float* __restrict__ bb)
{
    int ch = blockIdx.x * blockDim.x + threadIdx.x;
    if (ch < COUT) {
        const float invN = 1.f / (float)NSTAT;
        float mean = sum[ch] * invN;
        float var  = sq[ch] * invN - mean * mean;
        float rstd = rsqrtf(var + BN_EPS);
        float av = gamma[ch] * rstd;
        a[ch]  = av;
        bb[ch] = beta[ch] - mean * av;
    }
}

// ---------------- column sums of L per group: lcs[g][p] = sum_k L[g,k,p]
__global__ void k_lcs(const float* __restrict__ L, float* __restrict__ lcs)
{
    const int g = blockIdx.x, p = threadIdx.x;
    if (p < KDIM) {
        float s = 0.f;
        for (int k = 0; k < KDIM; ++k) s += L[(g * KDIM + k) * KDIM + p];
        lcs[g * KDIM + p] = s;
    }
}

// ---------------- conv2 (MFMA): h2(fp32 std, d_out) = W2 * elu(affine(h)); fused BN2 stats
__global__ __launch_bounds__(256) void k_conv2(
    const __bf16* __restrict__ h, const float* __restrict__ W2,
    const float* __restrict__ a1, const float* __restrict__ b1,
    float* __restrict__ h2, float* __restrict__ sum2, float* __restrict__ sq2)
{
    __shared__ __bf16 wl[COUT_G * 104];          // pad 96->104: stride 208B, conflict-free-ish
    __shared__ float a1l[COUT_G], b1l[COUT_G];
    __shared__ float st[COUT_G * 2];
    const int b = blockIdx.z, g = blockIdx.y;
    for (int i = threadIdx.x; i < COUT_G * COUT_G; i += 256) {
        const int o = i / COUT_G, c = i - o * COUT_G;
        wl[o * 104 + c] = (__bf16)W2[g * COUT_G * COUT_G + i];
    }
    if (threadIdx.x < COUT_G) {
        a1l[threadIdx.x] = a1[g * COUT_G + threadIdx.x];
        b1l[threadIdx.x] = b1[g * COUT_G + threadIdx.x];
    }
    if (threadIdx.x < COUT_G * 2) st[threadIdx.x] = 0.f;
    __syncthreads();

    const int wid = threadIdx.x >> 6, lane = threadIdx.x & 63;
    const int lg = lane >> 4, lr = lane & 15;
    const int pos0 = blockIdx.x * 256 + wid * 64;

    const __bf16* hb = h + (((size_t)b * G + g) * C8H) * NPOS * 8;

    f32x4 acc[6][4];
#pragma unroll
    for (int mt = 0; mt < 6; ++mt)
#pragma unroll
        for (int nt = 0; nt < 4; ++nt) acc[mt][nt] = (f32x4){0.f,0.f,0.f,0.f};

#pragma unroll
    for (int ks = 0; ks < 3; ++ks) {
        const int c0 = ks * 32 + lg * 8;
        bf16x8 af[6];
#pragma unroll
        for (int mt = 0; mt < 6; ++mt)
            af[mt] = *(const bf16x8*)&wl[(mt * 16 + lr) * 104 + c0];
        float av[8], bv[8];
#pragma unroll
        for (int i = 0; i < 8; ++i) { av[i] = a1l[c0 + i]; bv[i] = b1l[c0 + i]; }
#pragma unroll
        for (int nt = 0; nt < 4; ++nt) {
            const int pos = pos0 + nt * 16 + lr;
            const bf16x8 hv = *(const bf16x8*)&hb[((size_t)(ks * 4 + lg) * NPOS + pos) * 8];
            bf16x8 ef;
#pragma unroll
            for (int i = 0; i < 8; ++i) {
                float t = av[i] * (float)hv[i] + bv[i];
                t = t > 0.f ? t : (__expf(t) - 1.f);
                ef[i] = (__bf16)t;
            }
#pragma unroll
            for (int mt = 0; mt < 6; ++mt)
                acc[mt][nt] = __builtin_amdgcn_mfma_f32_16x16x32_bf16(af[mt], ef, acc[mt][nt], 0, 0, 0);
        }
    }

    float* ob = h2 + ((size_t)b * COUT + g * COUT_G) * NPOS;
#pragma unroll
    for (int mt = 0; mt < 6; ++mt) {
        const int o0 = mt * 16 + lg * 4;
#pragma unroll
        for (int nt = 0; nt < 4; ++nt) {
            const int pos = pos0 + nt * 16 + lr;
#pragma unroll
            for (int r = 0; r < 4; ++r)
                ob[(size_t)(o0 + r) * NPOS + pos] = acc[mt][nt][r];
        }
    }

    // fused stats
#pragma unroll
    for (int mt = 0; mt < 6; ++mt) {
#pragma unroll
        for (int r = 0; r < 4; ++r) {
            float s = 0.f, q = 0.f;
#pragma unroll
            for (int nt = 0; nt < 4; ++nt) {
                const float v = acc[mt][nt][r];
                s += v; q += v * v;
            }
#pragma unroll
            for (int m = 1; m <= 8; m <<= 1) {
                s += __shfl_xor(s, m);
                q += __shfl_xor(q, m);
            }
            if (lr == 0) {
                atomicAdd(&st[(mt * 16 + lg * 4 + r) * 2], s);
                atomicAdd(&st[(mt * 16 + lg * 4 + r) * 2 + 1], q);
            }
        }
    }
    __syncthreads();
    if (threadIdx.x < COUT_G) {
        atomicAdd(&sum2[g * COUT_G + threadIdx.x], st[threadIdx.x * 2]);
        atomicAdd(&sq2[g * COUT_G + threadIdx.x], st[threadIdx.x * 2 + 1]);
    }
}

// ---------------- adjacency (MFMA, in-place on d_out):
// y[j,p] = a2 * (h2[j,:] @ L[:,p]) + b2 * colsum(L)[p], per (b,ch) slab
__global__ __launch_bounds__(256) void k_adj(
    float* __restrict__ y, const float* __restrict__ L,
    const float* __restrict__ a2, const float* __restrict__ b2,
    const float* __restrict__ lcs)
{
    __shared__ __bf16 Lt[64 * 72];     // Lt[p][k] transposed, zero-padded, row stride 144B
    const int ch = blockIdx.x, b = blockIdx.y;
    const int g = ch / COUT_G;
    const float av = a2[ch], bv = b2[ch];
    float* slab = y + ((size_t)(b * COUT + ch)) * NPOS;
    const float* Lg = L + g * KDIM * KDIM;

    for (int i = threadIdx.x; i < 64 * 64; i += 256) {
        const int p = i >> 6, k = i & 63;
        const float v = (p < KDIM && k < KDIM) ? Lg[k * KDIM + p] : 0.f;
        Lt[p * 72 + k] = (__bf16)v;
    }
    __syncthreads();

    const int wid = threadIdx.x >> 6, lane = threadIdx.x & 63;
    const int lg = lane >> 4, lr = lane & 15;
    const int j0 = wid * 64;           // each wave owns rows [j0, j0+64) exclusively

    // register-stage all A fragments (reads) before any store to the same slab
    bf16x8 af[4][2];
#pragma unroll
    for (int mt = 0; mt < 4; ++mt)
#pragma unroll
        for (int ks = 0; ks < 2; ++ks) {
            const int row = j0 + mt * 16 + lr;
            const int k0 = ks * 32 + lg * 8;
            bf16x8 t;
#pragma unroll
            for (int i = 0; i < 8; ++i) {
                const int kk = k0 + i;
                float v = 0.f;
                if (kk < KDIM) v = slab[row * KDIM + kk];
                t[i] = (__bf16)v;
            }
            af[mt][ks] = t;
        }

    bf16x8 bt[4][2];
#pragma unroll
    for (int nt = 0; nt < 4; ++nt)
#pragma unroll
        for (int ks = 0; ks < 2; ++ks)
            bt[nt][ks] = *(const bf16x8*)&Lt[(nt * 16 + lr) * 72 + ks * 32 + lg * 8];

    f32x4 acc[4][4];
#pragma unroll
    for (int mt = 0; mt < 4; ++mt)
#pragma unroll
        for (int nt = 0; nt < 4; ++nt) acc[mt][nt] = (f32x4){0.f,0.f,0.f,0.f};

#pragma unroll
    for (int ks = 0; ks < 2; ++ks)
#pragma unroll
        for (int nt = 0; nt < 4; ++nt)
#pragma unroll
            for (int mt = 0; mt < 4; ++mt)
                acc[mt][nt] = __builtin_amdgcn_mfma_f32_16x16x32_bf16(af[mt][ks], bt[nt][ks], acc[mt][nt], 0, 0, 0);

#pragma unroll
    for (int nt = 0; nt < 4; ++nt) {
        const int p = nt * 16 + lr;
        if (p < KDIM) {
            const float csv = lcs[g * KDIM + p];
#pragma unroll
            for (int mt = 0; mt < 4; ++mt) {
                const int j = j0 + mt * 16 + lg * 4;
#pragma unroll
                for (int r = 0; r < 4; ++r)
                    slab[(j + r) * KDIM + p] = av * acc[mt][nt][r] + bv * csv;
            }
        }
    }
}

extern "C" void kernel_launch(void* const* d_in, const int* in_sizes, int n_in,
                              void* d_out, int out_size, void* d_ws, size_t ws_size,
                              hipStream_t stream)
{
    const float* x      = (const float*)d_in[0];
    const float* L      = (const float*)d_in[1];
    const float* W1     = (const float*)d_in[2];
    const float* W2     = (const float*)d_in[3];
    const float* gamma1 = (const float*)d_in[4];
    const float* beta1  = (const float*)d_in[5];
    const float* gamma2 = (const float*)d_in[6];
    const float* beta2  = (const float*)d_in[7];
    float* h2 = (float*)d_out;

    __bf16* h = (__bf16*)d_ws;
    const size_t hbytes = (size_t)B * COUT * NPOS * sizeof(__bf16);   // ~122 MB
    float* stats = (float*)((char*)d_ws + hbytes);
    float* sum1 = stats;        float* sq1 = stats + 480;
    float* sum2 = stats + 960;  float* sq2 = stats + 1440;
    float* a1   = stats + 1920; float* b1  = stats + 2400;
    float* a2   = stats + 2880; float* b2  = stats + 3360;
    float* lcs  = stats + 3840;                       // 5*62 floats

    hipMemsetAsync(stats, 0, 4 * 480 * sizeof(float), stream);

    dim3 gridc(NPOS_TILES, G, B);        // 62 x 5 x 8
    dim3 grida(COUT, B);                 // 480 x 8

    k_conv1<<<gridc, 256, 0, stream>>>(x, W1, h, sum1, sq1);
    k_finalize<<<2, 256, 0, stream>>>(sum1, sq1, gamma1, beta1, a1, b1);
    k_lcs<<<G, 64, 0, stream>>>(L, lcs);
    k_conv2<<<gridc, 256, 0, stream>>>(h, W2, a1, b1, h2, sum2, sq2);
    k_finalize<<<2, 256, 0, stream>>>(sum2, sq2, gamma2, beta2, a2, b2);
    k_adj<<<grida, 256, 0, stream>>>(h2, L, a2, b2, lcs);
}

// Round 4
// 311.584 us; speedup vs baseline: 3.1418x; 1.0669x over previous
//
#include <hip/hip_runtime.h>
#include <hip/hip_bf16.h>

#define G 5
#define B 8
#define CIN 320
#define CIN_G 64
#define COUT 480
#define COUT_G 96
#define NPOS 15872
#define PP 16384            // padded positions: 256 rows x 64 (k padded 62->64)
#define PP_TILES 64         // PP / 256
#define NSTAT (B*NPOS)
#define BN_EPS 1e-5f
#define KDIM 62
#define C8H 12
#define SLABBF 31744        // bf16 slots per (b,ch) slab region of d_out (15872 f32)

typedef float  f32x4  __attribute__((ext_vector_type(4)));
typedef __bf16 bf16x8 __attribute__((ext_vector_type(8)));
typedef __bf16 bf16x4 __attribute__((ext_vector_type(4)));

// ---------------- conv1 (MFMA): h[b][g][c8][pp][8] bf16 k-packed; fused BN1 stats
__global__ __launch_bounds__(256) void k_conv1(
    const float* __restrict__ x, const float* __restrict__ W1,
    __bf16* __restrict__ h, float* __restrict__ sum1, float* __restrict__ sq1)
{
    __shared__ __bf16 wl[COUT_G * 72];           // pad 64->72 vs bank conflicts
    __shared__ float st[COUT_G * 2];
    const int b = blockIdx.z, g = blockIdx.y;
    for (int i = threadIdx.x; i < COUT_G * CIN_G; i += 256) {
        const int o = i >> 6, c = i & 63;
        wl[o * 72 + c] = (__bf16)W1[g * COUT_G * CIN_G + i];
    }
    if (threadIdx.x < COUT_G * 2) st[threadIdx.x] = 0.f;
    __syncthreads();

    const int wid = threadIdx.x >> 6, lane = threadIdx.x & 63;
    const int lg = lane >> 4, lr = lane & 15;
    const int pos0 = blockIdx.x * 256 + wid * 64;   // pp base, multiple of 64
    const int jw = pos0 >> 6;                        // wave-uniform j row

    const float* xb = x + ((size_t)b * CIN + g * CIN_G) * NPOS;

    f32x4 acc[6][4];
#pragma unroll
    for (int mt = 0; mt < 6; ++mt)
#pragma unroll
        for (int nt = 0; nt < 4; ++nt) acc[mt][nt] = (f32x4){0.f,0.f,0.f,0.f};

#pragma unroll
    for (int ks = 0; ks < 2; ++ks) {
        const int c0 = ks * 32 + lg * 8;
        bf16x8 af[6];
#pragma unroll
        for (int mt = 0; mt < 6; ++mt)
            af[mt] = *(const bf16x8*)&wl[(mt * 16 + lr) * 72 + c0];
#pragma unroll
        for (int nt = 0; nt < 4; ++nt) {
            const int kcol = nt * 16 + lr;          // == pp & 63
            bf16x8 bfv;
            if (kcol < KDIM) {
                const float* xp = xb + jw * KDIM + kcol;
#pragma unroll
                for (int i = 0; i < 8; ++i)
                    bfv[i] = (__bf16)xp[(size_t)(c0 + i) * NPOS];
            } else {
#pragma unroll
                for (int i = 0; i < 8; ++i) bfv[i] = (__bf16)0.f;
            }
#pragma unroll
            for (int mt = 0; mt < 6; ++mt)
                acc[mt][nt] = __builtin_amdgcn_mfma_f32_16x16x32_bf16(af[mt], bfv, acc[mt][nt], 0, 0, 0);
        }
    }

    __bf16* hb = h + (((size_t)b * G + g) * C8H) * PP * 8;
#pragma unroll
    for (int mt = 0; mt < 6; ++mt) {
        const int o0 = mt * 16 + lg * 4;
        const size_t rowoff = (size_t)(o0 >> 3) * PP * 8 + (o0 & 7);
#pragma unroll
        for (int nt = 0; nt < 4; ++nt) {
            const int pp = pos0 + nt * 16 + lr;
            bf16x4 pv;
#pragma unroll
            for (int r = 0; r < 4; ++r) pv[r] = (__bf16)acc[mt][nt][r];
            *(bf16x4*)&hb[rowoff + (size_t)pp * 8] = pv;
        }
    }

    // fused BN1 stats (pad columns hold exact 0 -> contribute nothing)
#pragma unroll
    for (int mt = 0; mt < 6; ++mt) {
#pragma unroll
        for (int r = 0; r < 4; ++r) {
            float s = 0.f, q = 0.f;
#pragma unroll
            for (int nt = 0; nt < 4; ++nt) {
                const float v = acc[mt][nt][r];
                s += v; q += v * v;
            }
#pragma unroll
            for (int m = 1; m <= 8; m <<= 1) {
                s += __shfl_xor(s, m);
                q += __shfl_xor(q, m);
            }
            if (lr == 0) {
                atomicAdd(&st[(mt * 16 + lg * 4 + r) * 2], s);
                atomicAdd(&st[(mt * 16 + lg * 4 + r) * 2 + 1], q);
            }
        }
    }
    __syncthreads();
    if (threadIdx.x < COUT_G) {
        atomicAdd(&sum1[g * COUT_G + threadIdx.x], st[threadIdx.x * 2]);
        atomicAdd(&sq1[g * COUT_G + threadIdx.x], st[threadIdx.x * 2 + 1]);
    }
}

// ---------------- stats -> affine coefs
__global__ void k_finalize(const float* __restrict__ sum, const float* __restrict__ sq,
                           const float* __restrict__ gamma, const float* __restrict__ beta,
                           float* __restrict__ a, float* __restrict__ bb)
{
    int ch = blockIdx.x * blockDim.x + threadIdx.x;
    if (ch < COUT) {
        const float invN = 1.f / (float)NSTAT;
        float mean = sum[ch] * invN;
        float var  = sq[ch] * invN - mean * mean;
        float rstd = rsqrtf(var + BN_EPS);
        float av = gamma[ch] * rstd;
        a[ch]  = av;
        bb[ch] = beta[ch] - mean * av;
    }
}

// ---------------- column sums of L per group
__global__ void k_lcs(const float* __restrict__ L, float* __restrict__ lcs)
{
    const int g = blockIdx.x, p = threadIdx.x;
    if (p < KDIM) {
        float s = 0.f;
        for (int k = 0; k < KDIM; ++k) s += L[(g * KDIM + k) * KDIM + p];
        lcs[g * KDIM + p] = s;
    }
}

// ---------------- conv2 (MFMA, operands swapped: act=A, W2=B):
// h2b (bf16, sparse in d_out) = W2 * elu(affine(h)); fused BN2 stats
__global__ __launch_bounds__(256) void k_conv2(
    const __bf16* __restrict__ h, const float* __restrict__ W2,
    const float* __restrict__ a1, const float* __restrict__ b1,
    __bf16* __restrict__ h2b, float* __restrict__ sum2, float* __restrict__ sq2)
{
    __shared__ __bf16 wl[COUT_G * 104];          // pad 96->104
    __shared__ float a1l[COUT_G], b1l[COUT_G];
    __shared__ float st[COUT_G * 2];
    const int b = blockIdx.z, g = blockIdx.y;
    for (int i = threadIdx.x; i < COUT_G * COUT_G; i += 256) {
        const int o = i / COUT_G, c = i - o * COUT_G;
        wl[o * 104 + c] = (__bf16)W2[g * COUT_G * COUT_G + i];
    }
    if (threadIdx.x < COUT_G) {
        a1l[threadIdx.x] = a1[g * COUT_G + threadIdx.x];
        b1l[threadIdx.x] = b1[g * COUT_G + threadIdx.x];
    }
    if (threadIdx.x < COUT_G * 2) st[threadIdx.x] = 0.f;
    __syncthreads();

    const int wid = threadIdx.x >> 6, lane = threadIdx.x & 63;
    const int lg = lane >> 4, lr = lane & 15;
    const int pos0 = blockIdx.x * 256 + wid * 64;
    const int jw = pos0 >> 6;

    const __bf16* hbase = h + (((size_t)b * G + g) * C8H) * PP * 8;

    f32x4 acc[4][6];                             // [pos-tile][ch-tile]
#pragma unroll
    for (int mt = 0; mt < 4; ++mt)
#pragma unroll
        for (int nt = 0; nt < 6; ++nt) acc[mt][nt] = (f32x4){0.f,0.f,0.f,0.f};

#pragma unroll
    for (int ks = 0; ks < 3; ++ks) {
        const int c0 = ks * 32 + lg * 8;
        float av[8], bv[8];
#pragma unroll
        for (int i = 0; i < 8; ++i) { av[i] = a1l[c0 + i]; bv[i] = b1l[c0 + i]; }
        bf16x8 afr[4];                           // activation A-frags, ELU fused
#pragma unroll
        for (int mt = 0; mt < 4; ++mt) {
            const int pp = pos0 + mt * 16 + lr;
            const bf16x8 hv = *(const bf16x8*)&hbase[((size_t)(ks * 4 + lg) * PP + pp) * 8];
            const bool pad = (mt == 3) && (lr >= 14);  // pp&63 >= 62
            bf16x8 ef;
#pragma unroll
            for (int i = 0; i < 8; ++i) {
                float t = av[i] * (float)hv[i] + bv[i];
                t = t > 0.f ? t : (__expf(t) - 1.f);
                ef[i] = pad ? (__bf16)0.f : (__bf16)t;
            }
            afr[mt] = ef;
        }
        bf16x8 bw[6];                            // weight B-frags
#pragma unroll
        for (int nt = 0; nt < 6; ++nt)
            bw[nt] = *(const bf16x8*)&wl[(nt * 16 + lr) * 104 + c0];
#pragma unroll
        for (int mt = 0; mt < 4; ++mt)
#pragma unroll
            for (int nt = 0; nt < 6; ++nt)
                acc[mt][nt] = __builtin_amdgcn_mfma_f32_16x16x32_bf16(afr[mt], bw[nt], acc[mt][nt], 0, 0, 0);
    }

    // store bf16 h2b sparse in d_out: slab = b*COUT+ch, row jw, cols k
#pragma unroll
    for (int nt = 0; nt < 6; ++nt) {
        const int o = nt * 16 + lr;
        const size_t sbase = ((size_t)b * COUT + g * COUT_G + o) * SLABBF + (size_t)jw * 64;
#pragma unroll
        for (int mt = 0; mt < 4; ++mt) {
            const int kq = mt * 16 + lg * 4;     // multiple of 4 -> 8B aligned
            bf16x4 pv;
#pragma unroll
            for (int r = 0; r < 4; ++r) pv[r] = (__bf16)acc[mt][nt][r];
            *(bf16x4*)&h2b[sbase + kq] = pv;
        }
    }

    // fused BN2 stats: channel = nt*16+lr, sum over mt,r then lanes ^16,^32
#pragma unroll
    for (int nt = 0; nt < 6; ++nt) {
        float s = 0.f, q = 0.f;
#pragma unroll
        for (int mt = 0; mt < 4; ++mt)
#pragma unroll
            for (int r = 0; r < 4; ++r) {
                const float v = acc[mt][nt][r];
                s += v; q += v * v;
            }
        s += __shfl_xor(s, 16); q += __shfl_xor(q, 16);
        s += __shfl_xor(s, 32); q += __shfl_xor(q, 32);
        if (lane < 16) {
            atomicAdd(&st[(nt * 16 + lr) * 2], s);
            atomicAdd(&st[(nt * 16 + lr) * 2 + 1], q);
        }
    }
    __syncthreads();
    if (threadIdx.x < COUT_G) {
        atomicAdd(&sum2[g * COUT_G + threadIdx.x], st[threadIdx.x * 2]);
        atomicAdd(&sq2[g * COUT_G + threadIdx.x], st[threadIdx.x * 2 + 1]);
    }
}

// ---------------- adjacency (MFMA): y[j,p] = a2*(h2[j,:]@L[:,p]) + b2*lcs[p]
// reads bf16 h2b slab (head of its own d_out slab region), overwrites with fp32 y
__global__ __launch_bounds__(256) void k_adj(
    float* __restrict__ y, const float* __restrict__ L,
    const float* __restrict__ a2, const float* __restrict__ b2,
    const float* __restrict__ lcs)
{
    __shared__ __bf16 Lt[64 * 72];     // Lt[p][k], zero-padded
    const int ch = blockIdx.x, b = blockIdx.y;
    const int g = ch / COUT_G;
    const int s = b * COUT + ch;
    const float* Lg = L + g * KDIM * KDIM;
    const __bf16* h2b = (const __bf16*)y;

    for (int i = threadIdx.x; i < 64 * 64; i += 256) {
        const int p = i >> 6, k = i & 63;
        const float v = (p < KDIM && k < KDIM) ? Lg[k * KDIM + p] : 0.f;
        Lt[p * 72 + k] = (__bf16)v;
    }

    const int wid = threadIdx.x >> 6, lane = threadIdx.x & 63;
    const int lg = lane >> 4, lr = lane & 15;
    const int j0 = wid * 64;

    // register-stage ALL A-frags before the barrier; barrier drains vmcnt,
    // so no wave's later stores can affect another wave's loads
    bf16x8 af[4][2];
#pragma unroll
    for (int mt = 0; mt < 4; ++mt)
#pragma unroll
        for (int ks = 0; ks < 2; ++ks) {
            const int row = j0 + mt * 16 + lr;
            const int k0 = ks * 32 + lg * 8;
            af[mt][ks] = *(const bf16x8*)&h2b[(size_t)s * SLABBF + row * 64 + k0];
        }
    __syncthreads();

    bf16x8 bt[4][2];
#pragma unroll
    for (int nt = 0; nt < 4; ++nt)
#pragma unroll
        for (int ks = 0; ks < 2; ++ks)
            bt[nt][ks] = *(const bf16x8*)&Lt[(nt * 16 + lr) * 72 + ks * 32 + lg * 8];

    f32x4 acc[4][4];
#pragma unroll
    for (int mt = 0; mt < 4; ++mt)
#pragma unroll
        for (int nt = 0; nt < 4; ++nt) acc[mt][nt] = (f32x4){0.f,0.f,0.f,0.f};

#pragma unroll
    for (int ks = 0; ks < 2; ++ks)
#pragma unroll
        for (int nt = 0; nt < 4; ++nt)
#pragma unroll
            for (int mt = 0; mt < 4; ++mt)
                acc[mt][nt] = __builtin_amdgcn_mfma_f32_16x16x32_bf16(af[mt][ks], bt[nt][ks], acc[mt][nt], 0, 0, 0);

    const float av = a2[ch], bv = b2[ch];
#pragma unroll
    for (int nt = 0; nt < 4; ++nt) {
        const int p = nt * 16 + lr;
        if (p < KDIM) {
            const float csv = lcs[g * KDIM + p];
#pragma unroll
            for (int mt = 0; mt < 4; ++mt) {
                const int j = j0 + mt * 16 + lg * 4;
#pragma unroll
                for (int r = 0; r < 4; ++r)
                    y[(size_t)s * NPOS + (j + r) * KDIM + p] = av * acc[mt][nt][r] + bv * csv;
            }
        }
    }
}

extern "C" void kernel_launch(void* const* d_in, const int* in_sizes, int n_in,
                              void* d_out, int out_size, void* d_ws, size_t ws_size,
                              hipStream_t stream)
{
    const float* x      = (const float*)d_in[0];
    const float* L      = (const float*)d_in[1];
    const float* W1     = (const float*)d_in[2];
    const float* W2     = (const float*)d_in[3];
    const float* gamma1 = (const float*)d_in[4];
    const float* beta1  = (const float*)d_in[5];
    const float* gamma2 = (const float*)d_in[6];
    const float* beta2  = (const float*)d_in[7];
    float* y = (float*)d_out;

    __bf16* h = (__bf16*)d_ws;
    const size_t hbytes = (size_t)B * G * C8H * PP * 8 * sizeof(__bf16);  // ~126 MB
    float* stats = (float*)((char*)d_ws + hbytes);
    float* sum1 = stats;        float* sq1 = stats + 480;
    float* sum2 = stats + 960;  float* sq2 = stats + 1440;
    float* a1   = stats + 1920; float* b1  = stats + 2400;
    float* a2   = stats + 2880; float* b2  = stats + 3360;
    float* lcs  = stats + 3840;

    hipMemsetAsync(stats, 0, 4 * 480 * sizeof(float), stream);

    dim3 gridc(PP_TILES, G, B);          // 64 x 5 x 8
    dim3 grida(COUT, B);                 // 480 x 8

    k_conv1<<<gridc, 256, 0, stream>>>(x, W1, h, sum1, sq1);
    k_finalize<<<2, 256, 0, stream>>>(sum1, sq1, gamma1, beta1, a1, b1);
    k_lcs<<<G, 64, 0, stream>>>(L, lcs);
    k_conv2<<<gridc, 256, 0, stream>>>(h, W2, a1, b1, (__bf16*)d_out, sum2, sq2);
    k_finalize<<<2, 256, 0, stream>>>(sum2, sq2, gamma2, beta2, a2, b2);
    k_adj<<<grida, 256, 0, stream>>>(y, L, a2, b2, lcs);
}

// Round 5
// 308.583 us; speedup vs baseline: 3.1724x; 1.0097x over previous
//
#include <hip/hip_runtime.h>
#include <hip/hip_bf16.h>

#define G 5
#define B 8
#define CIN 320
#define CIN_G 64
#define COUT 480
#define COUT_G 96
#define NPOS 15872
#define NSTAT (B*NPOS)
#define BN_EPS 1e-5f
#define KDIM 62
#define SLABBF 31744        // bf16 slots per (b,ch) slab region of d_out

typedef float  f32x4 __attribute__((ext_vector_type(4)));
typedef float  f32x2 __attribute__((ext_vector_type(2)));
typedef __bf16 bf16x8 __attribute__((ext_vector_type(8)));
typedef __bf16 bf16x4 __attribute__((ext_vector_type(4)));

// ---------------- prep: W1,W2 -> bf16; L column sums
__global__ __launch_bounds__(256) void k_prep(
    const float* __restrict__ W1, const float* __restrict__ W2, const float* __restrict__ L,
    __bf16* __restrict__ W1b, __bf16* __restrict__ W2b, float* __restrict__ lcs)
{
    const int bx = blockIdx.x;
    if (bx < 300) {
        const int i = bx * 256 + threadIdx.x;
        if (i < 30720) W1b[i] = (__bf16)W1[i];
        else W2b[i - 30720] = (__bf16)W2[i - 30720];
    } else {
        const int g = bx - 300, p = threadIdx.x;
        if (p < KDIM) {
            float s = 0.f;
            for (int k = 0; k < KDIM; ++k) s += L[(g * KDIM + k) * KDIM + p];
            lcs[g * KDIM + p] = s;
        }
    }
}

// ---------------- covariance: C[g] += x_g x_g^T over (b,pos); xsum[g][c] row sums
// A-frag == B-frag (same registers). Fully vectorized x reads, no stores.
__global__ __launch_bounds__(256) void k_cov(
    const float* __restrict__ x, float* __restrict__ Cov, float* __restrict__ xsum)
{
    const int b = blockIdx.z, g = blockIdx.y, ck = blockIdx.x;   // ck: 0..30
    const int wid = threadIdx.x >> 6, lane = threadIdx.x & 63;
    const int lg = lane >> 4, lr = lane & 15;
    const float* xb = x + ((size_t)b * CIN + g * CIN_G) * NPOS;
    const int pbase = ck * 512 + wid * 128;       // wave's 128-pos slice (31*512 = NPOS exact)

    f32x4 acc[4][4];
#pragma unroll
    for (int mi = 0; mi < 4; ++mi)
#pragma unroll
        for (int mj = 0; mj < 4; ++mj) acc[mi][mj] = (f32x4){0.f,0.f,0.f,0.f};
    float rs[4] = {0.f,0.f,0.f,0.f};

#pragma unroll
    for (int kk = 0; kk < 4; ++kk) {
        const int pk = pbase + kk * 32 + lg * 8;
        bf16x8 fr[4];
#pragma unroll
        for (int mt = 0; mt < 4; ++mt) {
            const float* p = xb + (size_t)(mt * 16 + lr) * NPOS + pk;
            const f32x4 u0 = *(const f32x4*)p;
            const f32x4 u1 = *(const f32x4*)(p + 4);
            bf16x8 t;
#pragma unroll
            for (int i = 0; i < 4; ++i) { t[i] = (__bf16)u0[i]; t[4+i] = (__bf16)u1[i]; }
#pragma unroll
            for (int i = 0; i < 8; ++i) rs[mt] += (float)t[i];
            fr[mt] = t;
        }
#pragma unroll
        for (int mi = 0; mi < 4; ++mi)
#pragma unroll
            for (int mj = 0; mj < 4; ++mj)
                acc[mi][mj] = __builtin_amdgcn_mfma_f32_16x16x32_bf16(fr[mi], fr[mj], acc[mi][mj], 0, 0, 0);
    }

    float* Cg = Cov + g * 4096;
#pragma unroll
    for (int mi = 0; mi < 4; ++mi)
#pragma unroll
        for (int mj = 0; mj < 4; ++mj)
#pragma unroll
            for (int r = 0; r < 4; ++r)
                atomicAdd(&Cg[(mi * 16 + lg * 4 + r) * 64 + mj * 16 + lr], acc[mi][mj][r]);
#pragma unroll
    for (int mt = 0; mt < 4; ++mt) {
        float s = rs[mt];
        s += __shfl_xor(s, 16);
        s += __shfl_xor(s, 32);
        if (lg == 0) atomicAdd(&xsum[g * 64 + mt * 16 + lr], s);
    }
}

// ---------------- BN1 coefs from covariance: var_o = W1 C W1^T /N - mean^2
__global__ void k_fin1(const float* __restrict__ Cov, const float* __restrict__ xsum,
                       const __bf16* __restrict__ W1b,
                       const float* __restrict__ gamma, const float* __restrict__ beta,
                       float* __restrict__ a, float* __restrict__ bb)
{
    const int o = blockIdx.x;                     // 0..479
    const int g = o / COUT_G, og = o % COUT_G;
    const int t = threadIdx.x;                    // 0..63
    const __bf16* Wr = W1b + (size_t)(g * COUT_G + og) * 64;
    const float wt = (float)Wr[t];
    const float* Cr = Cov + g * 4096 + t * 64;
    float vp = 0.f;
    for (int c = 0; c < 64; ++c) vp += Cr[c] * (float)Wr[c];
    vp *= wt;
    float mp = wt * xsum[g * 64 + t];
#pragma unroll
    for (int m = 1; m <= 32; m <<= 1) { vp += __shfl_xor(vp, m); mp += __shfl_xor(mp, m); }
    if (t == 0) {
        const float invN = 1.f / (float)NSTAT;
        const float mean = mp * invN;
        const float var  = vp * invN - mean * mean;
        const float rstd = rsqrtf(var + BN_EPS);
        const float av = gamma[o] * rstd;
        a[o]  = av;
        bb[o] = beta[o] - mean * av;
    }
}

// ---------------- fused: recompute h=W1@x, BN1+ELU, conv2 -> h2 bf16 (in d_out); BN2 stats
__global__ __launch_bounds__(256, 2) void k_fused(
    const float* __restrict__ x, const __bf16* __restrict__ W1b, const __bf16* __restrict__ W2b,
    const float* __restrict__ a1, const float* __restrict__ b1,
    __bf16* __restrict__ h2b, float* __restrict__ sum2, float* __restrict__ sq2)
{
    __shared__ __bf16 wl[COUT_G * 72];            // 13824 B, row stride 144B (16B mult)
    __shared__ __bf16 ht[4 * 6144];               // 49152 B: 4 waves x (12 c8 x 64 pos x 8) swizzled
    __shared__ float a1l[96], b1l[96], st[192];
    const int b = blockIdx.z, g = blockIdx.y;
    for (int i = threadIdx.x; i < 768; i += 256) {          // 768 x bf16x8 = 6144
        const int idx = i * 8, o = idx >> 6, c = idx & 63;
        *(bf16x8*)&wl[o * 72 + c] = *(const bf16x8*)&W1b[g * 6144 + idx];
    }
    if (threadIdx.x < 96) {
        a1l[threadIdx.x] = a1[g * 96 + threadIdx.x];
        b1l[threadIdx.x] = b1[g * 96 + threadIdx.x];
    }
    if (threadIdx.x < 192) st[threadIdx.x] = 0.f;
    __syncthreads();

    const int wid = threadIdx.x >> 6, lane = threadIdx.x & 63;
    const int lg = lane >> 4, lr = lane & 15;
    const int jw = blockIdx.x * 4 + wid;          // wave's j row (0..255)
    const float* xb = x + ((size_t)b * CIN + g * CIN_G) * NPOS;
    char* htw = (char*)(ht + wid * 6144);

    // ---- phase 1: C1[o][pos] = W1 @ x ; BN1+ELU ; swizzled k-packed LDS write
    {
        f32x4 acc1[6][4];
#pragma unroll
        for (int mt = 0; mt < 6; ++mt)
#pragma unroll
            for (int nt = 0; nt < 4; ++nt) acc1[mt][nt] = (f32x4){0.f,0.f,0.f,0.f};

#pragma unroll
        for (int ks = 0; ks < 2; ++ks) {
            const int c0 = ks * 32 + lg * 8;
            bf16x8 af[6];
#pragma unroll
            for (int mt = 0; mt < 6; ++mt)
                af[mt] = *(const bf16x8*)&wl[(mt * 16 + lr) * 72 + c0];
#pragma unroll
            for (int nt = 0; nt < 4; ++nt) {
                const int kcol = nt * 16 + lr;
                bf16x8 bfv;
                if (kcol < KDIM) {
                    const float* xp = xb + jw * KDIM + kcol;
#pragma unroll
                    for (int i = 0; i < 8; ++i) bfv[i] = (__bf16)xp[(size_t)(c0 + i) * NPOS];
                } else {
#pragma unroll
                    for (int i = 0; i < 8; ++i) bfv[i] = (__bf16)0.f;
                }
#pragma unroll
                for (int mt = 0; mt < 6; ++mt)
                    acc1[mt][nt] = __builtin_amdgcn_mfma_f32_16x16x32_bf16(af[mt], bfv, acc1[mt][nt], 0, 0, 0);
            }
        }
#pragma unroll
        for (int mt = 0; mt < 6; ++mt) {
            const int o0 = mt * 16 + lg * 4;
            const int c8 = o0 >> 3;               // = mt*2 + (lg>>1)
            const int half = (o0 & 7) >> 2;       // = lg&1
#pragma unroll
            for (int nt = 0; nt < 4; ++nt) {
                const int pl = nt * 16 + lr;
                bf16x4 pv;
#pragma unroll
                for (int r = 0; r < 4; ++r) {
                    const int o = o0 + r;
                    float t = a1l[o] * acc1[mt][nt][r] + b1l[o];
                    t = t > 0.f ? t : (__expf(t) - 1.f);
                    pv[r] = (__bf16)t;
                }
                *(bf16x4*)(htw + c8 * 1024 + (pl ^ ((c8 & 3) << 1)) * 16 + half * 8) = pv;
            }
        }
    }
    // wave-private LDS: compiler orders ds_write -> ds_read via lgkmcnt; no barrier needed

    // ---- phase 2: acc2[pos][ch] = eh @ W2^T
    f32x4 acc2[4][6];
#pragma unroll
    for (int mt = 0; mt < 4; ++mt)
#pragma unroll
        for (int nt = 0; nt < 6; ++nt) acc2[mt][nt] = (f32x4){0.f,0.f,0.f,0.f};

#pragma unroll
    for (int ks = 0; ks < 3; ++ks) {
        const int c0 = ks * 32 + lg * 8;
        const int c8r = ks * 4 + lg;
        bf16x8 a2[4];
#pragma unroll
        for (int mt = 0; mt < 4; ++mt) {
            a2[mt] = *(const bf16x8*)(htw + c8r * 1024 + ((mt * 16 + lr) ^ ((c8r & 3) << 1)) * 16);
            if (mt == 3 && lr >= 14) {            // pad pos 62,63 -> zero rows
#pragma unroll
                for (int i = 0; i < 8; ++i) a2[mt][i] = (__bf16)0.f;
            }
        }
        bf16x8 bw[6];
#pragma unroll
        for (int nt = 0; nt < 6; ++nt)
            bw[nt] = *(const bf16x8*)&W2b[((size_t)g * 96 + nt * 16 + lr) * 96 + c0];
#pragma unroll
        for (int mt = 0; mt < 4; ++mt)
#pragma unroll
            for (int nt = 0; nt < 6; ++nt)
                acc2[mt][nt] = __builtin_amdgcn_mfma_f32_16x16x32_bf16(a2[mt], bw[nt], acc2[mt][nt], 0, 0, 0);
    }

    // store h2 bf16 (sparse in d_out) + BN2 stats
#pragma unroll
    for (int nt = 0; nt < 6; ++nt) {
        const int o2 = nt * 16 + lr;
        __bf16* sb = h2b + ((size_t)b * COUT + g * 96 + o2) * SLABBF + (size_t)jw * 64;
        float s = 0.f, q = 0.f;
#pragma unroll
        for (int mt = 0; mt < 4; ++mt) {
            bf16x4 pv;
#pragma unroll
            for (int r = 0; r < 4; ++r) {
                const float v = acc2[mt][nt][r];
                s += v; q += v * v;
                pv[r] = (__bf16)v;
            }
            *(bf16x4*)&sb[mt * 16 + lg * 4] = pv;
        }
        s += __shfl_xor(s, 16); q += __shfl_xor(q, 16);
        s += __shfl_xor(s, 32); q += __shfl_xor(q, 32);
        if (lane < 16) {
            atomicAdd(&st[o2 * 2], s);
            atomicAdd(&st[o2 * 2 + 1], q);
        }
    }
    __syncthreads();
    if (threadIdx.x < 96) {
        atomicAdd(&sum2[g * 96 + threadIdx.x], st[threadIdx.x * 2]);
        atomicAdd(&sq2[g * 96 + threadIdx.x], st[threadIdx.x * 2 + 1]);
    }
}

// ---------------- BN2 coefs
__global__ void k_fin2(const float* __restrict__ sum, const float* __restrict__ sq,
                       const float* __restrict__ gamma, const float* __restrict__ beta,
                       float* __restrict__ a, float* __restrict__ bb)
{
    const int ch = blockIdx.x * blockDim.x + threadIdx.x;
    if (ch < COUT) {
        const float invN = 1.f / (float)NSTAT;
        const float mean = sum[ch] * invN;
        const float var  = sq[ch] * invN - mean * mean;
        const float rstd = rsqrtf(var + BN_EPS);
        const float av = gamma[ch] * rstd;
        a[ch]  = av;
        bb[ch] = beta[ch] - mean * av;
    }
}

// ---------------- adjacency (MFMA, swapped: A=L^T, B=h2^T -> C[p][j]); in-place on d_out
__global__ __launch_bounds__(256) void k_adj(
    float* __restrict__ y, const float* __restrict__ L,
    const float* __restrict__ a2, const float* __restrict__ b2,
    const float* __restrict__ lcs)
{
    __shared__ __bf16 Lt[64 * 72];     // Lt[p][k], zero-padded
    __shared__ float lcl[64];
    const int ch = blockIdx.x, b = blockIdx.y;
    const int g = ch / COUT_G;
    const int s = b * COUT + ch;
    const float* Lg = L + g * KDIM * KDIM;
    const __bf16* h2b = (const __bf16*)y;

    for (int i = threadIdx.x; i < 4096; i += 256) {
        const int p = i >> 6, k = i & 63;
        Lt[p * 72 + k] = (__bf16)((p < KDIM && k < KDIM) ? Lg[k * KDIM + p] : 0.f);
    }
    if (threadIdx.x < 64)
        lcl[threadIdx.x] = (threadIdx.x < KDIM) ? lcs[g * KDIM + threadIdx.x] : 0.f;

    const int wid = threadIdx.x >> 6, lane = threadIdx.x & 63;
    const int lg = lane >> 4, lr = lane & 15;
    const int j0 = wid * 64;

    // stage ALL h2 B-frags before the barrier (barrier drains vmcnt -> safe in-place)
    bf16x8 bt[4][2];
#pragma unroll
    for (int nt = 0; nt < 4; ++nt)
#pragma unroll
        for (int ks = 0; ks < 2; ++ks)
            bt[nt][ks] = *(const bf16x8*)&h2b[(size_t)s * SLABBF + (j0 + nt * 16 + lr) * 64 + ks * 32 + lg * 8];
    __syncthreads();

    bf16x8 lt[4][2];
#pragma unroll
    for (int mt = 0; mt < 4; ++mt)
#pragma unroll
        for (int ks = 0; ks < 2; ++ks)
            lt[mt][ks] = *(const bf16x8*)&Lt[(mt * 16 + lr) * 72 + ks * 32 + lg * 8];

    f32x4 acc[4][4];
#pragma unroll
    for (int mt = 0; mt < 4; ++mt)
#pragma unroll
        for (int nt = 0; nt < 4; ++nt) acc[mt][nt] = (f32x4){0.f,0.f,0.f,0.f};

#pragma unroll
    for (int ks = 0; ks < 2; ++ks)
#pragma unroll
        for (int nt = 0; nt < 4; ++nt)
#pragma unroll
            for (int mt = 0; mt < 4; ++mt)
                acc[mt][nt] = __builtin_amdgcn_mfma_f32_16x16x32_bf16(lt[mt][ks], bt[nt][ks], acc[mt][nt], 0, 0, 0);

    const float av = a2[ch], bv = b2[ch];
#pragma unroll
    for (int nt = 0; nt < 4; ++nt) {
        const int j = j0 + nt * 16 + lr;
        float* yr = y + (size_t)s * NPOS + j * KDIM;
#pragma unroll
        for (int mt = 0; mt < 4; ++mt) {
            const int p0 = mt * 16 + lg * 4;
            f32x2 v0 = { av * acc[mt][nt][0] + bv * lcl[p0],
                         av * acc[mt][nt][1] + bv * lcl[p0 + 1] };
            *(f32x2*)&yr[p0] = v0;
            if (p0 < 60) {
                f32x2 v1 = { av * acc[mt][nt][2] + bv * lcl[p0 + 2],
                             av * acc[mt][nt][3] + bv * lcl[p0 + 3] };
                *(f32x2*)&yr[p0 + 2] = v1;
            }
        }
    }
}

extern "C" void kernel_launch(void* const* d_in, const int* in_sizes, int n_in,
                              void* d_out, int out_size, void* d_ws, size_t ws_size,
                              hipStream_t stream)
{
    const float* x      = (const float*)d_in[0];
    const float* L      = (const float*)d_in[1];
    const float* W1     = (const float*)d_in[2];
    const float* W2     = (const float*)d_in[3];
    const float* gamma1 = (const float*)d_in[4];
    const float* beta1  = (const float*)d_in[5];
    const float* gamma2 = (const float*)d_in[6];
    const float* beta2  = (const float*)d_in[7];
    float* y = (float*)d_out;

    float* ws   = (float*)d_ws;
    float* Cov  = ws;                    // 5*4096 = 20480
    float* xsum = ws + 20480;            // 320
    float* sum2 = ws + 20800;            // 480
    float* sq2  = ws + 21280;            // 480
    float* a1   = ws + 21760;            // 480
    float* b1   = ws + 22240;            // 480
    float* a2   = ws + 22720;            // 480
    float* b2   = ws + 23200;            // 480
    float* lcs  = ws + 23680;            // 310 (pad to 24064)
    __bf16* W1b = (__bf16*)(ws + 24064); // 30720 bf16
    __bf16* W2b = (__bf16*)(ws + 24064 + 15360); // 46080 bf16

    hipMemsetAsync(ws, 0, 21760 * sizeof(float), stream);   // Cov + xsum + sum2 + sq2

    k_prep <<<305, 256, 0, stream>>>(W1, W2, L, W1b, W2b, lcs);
    k_cov  <<<dim3(31, G, B), 256, 0, stream>>>(x, Cov, xsum);
    k_fin1 <<<COUT, 64, 0, stream>>>(Cov, xsum, W1b, gamma1, beta1, a1, b1);
    k_fused<<<dim3(64, G, B), 256, 0, stream>>>(x, W1b, W2b, a1, b1, (__bf16*)d_out, sum2, sq2);
    k_fin2 <<<2, 256, 0, stream>>>(sum2, sq2, gamma2, beta2, a2, b2);
    k_adj  <<<dim3(COUT, B), 256, 0, stream>>>(y, L, a2, b2, lcs);
}